// Round 15
// baseline (253.136 us; speedup 1.0000x reference)
//
#include <hip/hip_runtime.h>
#include <hip/hip_bf16.h>

// Sizes (fixed by the reference)
#define BATCH 8192
#define DIM   128
#define NPAT  64
#define VOCAB 32000
#define CHUNKS (BATCH / 16)   // 512 16-row A chunks

// GEMM geometry (R15): 1000 blocks x 64 thr (1 wave). Wave owns 256 cols
// (16 tiles, b[16][4] = 256 VGPR) and sweeps 64 chunks. Stores go through a
// 16-KB XOR-swizzled LDS pad -> each store instruction is 1024 B FULLY
// CONTIGUOUS in ONE output row (fill-kernel instruction shape). Run-length
// curve: 64B=2.95, 256B=4.4, 512B=5.0 TB/s; this tests the 1024-B max.
#define NPANEL  125
#define NSPLITS 8
#define CPB     (CHUNKS / NSPLITS)    // 64 chunks per wave

typedef __attribute__((ext_vector_type(8))) short short8;   // 8 bf16 = 4 VGPRs
typedef __attribute__((ext_vector_type(4))) float f32x4;    // MFMA accum

// ---------------------------------------------------------------------------
// Phase A: per-row attention/softmax/rec/self-gate, all f32, output gated bf16.
// One wave per batch row, 4 rows (4 waves) per block.  (proven, ~15 us)
// ---------------------------------------------------------------------------
__global__ __launch_bounds__(256) void phaseA_kernel(
    const float* __restrict__ x,            // [B, D]
    const float* __restrict__ attn_w,       // [D, P]
    const float* __restrict__ attn_b,       // [P]
    const float* __restrict__ pattern_dict, // [P, D]
    const float* __restrict__ self_w,       // [D, D]
    const float* __restrict__ self_b,       // [D]
    __hip_bfloat16* __restrict__ gated)     // [B, D] bf16 out
{
    __shared__ float xs[4][DIM];
    __shared__ float wls[4][NPAT];
    __shared__ float recs[4][DIM];

    const int lane = threadIdx.x & 63;
    const int wid  = threadIdx.x >> 6;
    const int row  = blockIdx.x * 4 + wid;

    xs[wid][lane]      = x[row * DIM + lane];
    xs[wid][lane + 64] = x[row * DIM + 64 + lane];
    __syncthreads();

    float acc = attn_b[lane];
#pragma unroll 8
    for (int d = 0; d < DIM; ++d)
        acc += xs[wid][d] * attn_w[d * NPAT + lane];

    float m = acc;
#pragma unroll
    for (int o = 32; o; o >>= 1) m = fmaxf(m, __shfl_xor(m, o));
    float e = expf(acc - m);
    float s = e;
#pragma unroll
    for (int o = 32; o; o >>= 1) s += __shfl_xor(s, o);
    float w = e / s;
    wls[wid][lane] = w;
    __syncthreads();

    float r0 = 0.f, r1 = 0.f;
#pragma unroll 8
    for (int p = 0; p < NPAT; ++p) {
        float wp = wls[wid][p];
        r0 += wp * pattern_dict[p * DIM + lane];
        r1 += wp * pattern_dict[p * DIM + 64 + lane];
    }
    recs[wid][lane]      = r0;
    recs[wid][lane + 64] = r1;
    __syncthreads();

    float s0 = self_b[lane], s1 = self_b[lane + 64];
#pragma unroll 8
    for (int k = 0; k < DIM; ++k) {
        float rk = recs[wid][k];
        s0 += rk * self_w[k * DIM + lane];
        s1 += rk * self_w[k * DIM + 64 + lane];
    }

    float p0 = s0 - r0, p1 = s1 - r1;
    float ss = p0 * p0 + p1 * p1;
#pragma unroll
    for (int o = 32; o; o >>= 1) ss += __shfl_xor(ss, o);
    float mag = sqrtf(ss);
    float g = 1.f / (1.f + expf(-mag));

    gated[row * DIM + lane]      = __float2bfloat16(r0 * g);
    gated[row * DIM + 64 + lane] = __float2bfloat16(r1 * g);
}

// ---------------------------------------------------------------------------
// Repack A: gated [B,D] bf16 -> Af fragment-major, 512 chunks x 4096 B.
// Af[((ch*4 + ks)*64 + lane)*8 + j] = gated[ch*16 + (lane&15)][ks*32 + (lane>>4)*8 + j]
// ---------------------------------------------------------------------------
__global__ __launch_bounds__(256) void repack_a_kernel(
    const __hip_bfloat16* __restrict__ gated,
    __hip_bfloat16* __restrict__ Af)
{
    const int lane = threadIdx.x & 63;
    const int wv   = threadIdx.x >> 6;    // 0..3
    const int ch   = blockIdx.x * 4 + wv; // 0..511
    const int r16  = lane & 15;
    const int kq   = lane >> 4;
#pragma unroll
    for (int ks = 0; ks < 4; ++ks) {
        short8 v = *reinterpret_cast<const short8*>(
            gated + (size_t)(ch * 16 + r16) * DIM + ks * 32 + kq * 8);
        *reinterpret_cast<short8*>(
            Af + ((size_t)(ch * 4 + ks) * 64 + lane) * 8) = v;
    }
}

// ---------------------------------------------------------------------------
// Repack W: out_w [D=128, V] f32 -> Bf fragment-major bf16 (proven R5-R14).
// ---------------------------------------------------------------------------
__global__ __launch_bounds__(256) void repack_w_kernel(
    const float* __restrict__ out_w,        // [D, V]
    __hip_bfloat16* __restrict__ Bf)        // fragment-major [2000*4*64*8]
{
    __shared__ __hip_bfloat16 tile[64][136];

    const int t  = threadIdx.x;
    const int n0 = blockIdx.x * 64;
    const int c  = t & 63;
    const int k0 = t >> 6;

    for (int kk = 0; kk < DIM; kk += 4) {
        int k = kk + k0;
        tile[c][k] = __float2bfloat16(out_w[(size_t)k * VOCAB + n0 + c]);
    }
    __syncthreads();

    const int lane = t & 63;
    const int tl   = t >> 6;
    const int r16  = lane & 15;
    const int kq   = lane >> 4;
    const int gt   = (n0 >> 4) + tl;
#pragma unroll
    for (int ks = 0; ks < 4; ++ks) {
        uint4 v = *reinterpret_cast<const uint4*>(&tile[tl * 16 + r16][ks * 32 + kq * 8]);
        *reinterpret_cast<uint4*>(Bf + ((size_t)(gt * 4 + ks) * 64 + lane) * 8) = v;
    }
}

// ---------------------------------------------------------------------------
// GEMM (R15): 1-wave blocks, 256-col panels -> 1024-B single-row store
// instructions (the max a wave-store can express; fill-kernel shape).
// b[16][4] (256 VGPR) loaded once; acc 64 + A ping-pong 32 + misc ~370 VGPR
// -> 1 wave/SIMD (4 blocks/CU; fill achieves 6.9 TB/s at ~3.6 waves/CU).
// Per iter: 4 prefetched L2 A-loads, 64 MFMA, 16+16 swizzled LDS pad
// instrs (8-cyc inherent bank-wrap floor each), 16 x 1024-B row stores.
// Barrier-free, no inline asm; bias = one f32x4/lane (store cols fixed).
// ---------------------------------------------------------------------------
__global__ __launch_bounds__(64) void gemm_kernel(
    const __hip_bfloat16* __restrict__ Af,  // fragment-major A
    const __hip_bfloat16* __restrict__ Bf,  // fragment-major W
    const float* __restrict__ bias,         // [V]
    float* __restrict__ out)                // [B, V]
{
    __shared__ char pad[16384];             // 16 rows x 1024 B (wave-private)

    const int lane  = threadIdx.x & 63;
    const int r16   = lane & 15;
    const int kq    = lane >> 4;            // 0..3
    const int panel = blockIdx.x % NPANEL;
    const int split = blockIdx.x / NPANEL;  // 0..7
    const int col0  = panel * 256;
    const int t0    = panel * 16;           // first of 16 n-tiles
    const int ch0   = split * CPB;

    // B fragments for this wave's 16 tiles: registers for the whole kernel.
    short8 b[16][4];
#pragma unroll
    for (int t = 0; t < 16; ++t)
#pragma unroll
        for (int ks = 0; ks < 4; ++ks)
            b[t][ks] = *reinterpret_cast<const short8*>(
                Bf + ((size_t)((t0 + t) * 4 + ks) * 64 + lane) * 8);

    // bias: each lane's store columns are fixed -> one f32x4 for the kernel.
    const f32x4 bb = *reinterpret_cast<const f32x4*>(bias + col0 + lane * 4);

    auto aload = [&](int ch, short8* a) {
#pragma unroll
        for (int ks = 0; ks < 4; ++ks)
            a[ks] = *reinterpret_cast<const short8*>(
                Af + ((size_t)(ch * 4 + ks) * 64 + lane) * 8);
    };

    short8 a0[4], a1[4];
    aload(ch0, a0);                          // prologue: first chunk

#pragma unroll 2
    for (int c = 0; c < CPB; ++c) {
        short8* acur = (c & 1) ? a1 : a0;
        short8* anxt = (c & 1) ? a0 : a1;
        const int ch = ch0 + c;

        if (c + 1 < CPB) aload(ch + 1, anxt); // prefetch next chunk into regs

        f32x4 acc[16];
#pragma unroll
        for (int t = 0; t < 16; ++t) {
            f32x4 z = {};
#pragma unroll
            for (int ks = 0; ks < 4; ++ks)
                z = __builtin_amdgcn_mfma_f32_16x16x32_bf16(
                    b[t][ks], acur[ks], z, 0, 0, 0);
            acc[t] = z;
        }

        // ---- pad write: row r16, colbytes t*64 + kq*16, XOR-swizzled ----
        // (any 1024-B wave LDS access wraps all 32 banks 8x; swizzle keeps
        //  the wrap uniform -> 8-cyc floor, no excess conflicts)
#pragma unroll
        for (int t = 0; t < 16; ++t) {
            const int pb = r16 * 1024 + ((t * 64 + kq * 16) ^ ((r16 & 7) << 4));
            *reinterpret_cast<f32x4*>(pad + pb) = acc[t];
        }

        // ---- stores: 16 instrs, each 1024 B contiguous in ONE row ----
        const size_t orow0 = (size_t)ch * 16 * VOCAB + col0;
#pragma unroll
        for (int s = 0; s < 16; ++s) {
            const int pb = s * 1024 + ((lane * 16) ^ ((s & 7) << 4));
            f32x4 v = *reinterpret_cast<const f32x4*>(pad + pb);
            v += bb;
            *reinterpret_cast<f32x4*>(out + orow0 + (size_t)s * VOCAB + lane * 4) = v;
        }
    }
}

// ---------------------------------------------------------------------------
extern "C" void kernel_launch(void* const* d_in, const int* in_sizes, int n_in,
                              void* d_out, int out_size, void* d_ws, size_t ws_size,
                              hipStream_t stream) {
    const float* x            = (const float*)d_in[0];
    const float* pattern_dict = (const float*)d_in[1];
    const float* attn_w       = (const float*)d_in[2];
    const float* attn_b       = (const float*)d_in[3];
    const float* self_w       = (const float*)d_in[4];
    const float* self_b       = (const float*)d_in[5];
    const float* out_w        = (const float*)d_in[6];
    const float* out_b        = (const float*)d_in[7];
    float* out = (float*)d_out;

    // ws: gated 2 MB | Af 2 MB | Bf 8.2 MB
    __hip_bfloat16* gated = (__hip_bfloat16*)d_ws;
    __hip_bfloat16* Af    = (__hip_bfloat16*)((char*)d_ws + (size_t)BATCH * DIM * 2);
    __hip_bfloat16* Bf    = (__hip_bfloat16*)((char*)d_ws + (size_t)2 * BATCH * DIM * 2);

    phaseA_kernel<<<BATCH / 4, 256, 0, stream>>>(
        x, attn_w, attn_b, pattern_dict, self_w, self_b, gated);
    repack_a_kernel<<<CHUNKS / 4, 256, 0, stream>>>(gated, Af);
    repack_w_kernel<<<VOCAB / 64, 256, 0, stream>>>(out_w, Bf);
    gemm_kernel<<<NPANEL * NSPLITS, 64, 0, stream>>>(Af, Bf, out_b, out);
}

// Round 16
// 240.609 us; speedup vs baseline: 1.0521x; 1.0521x over previous
//
#include <hip/hip_runtime.h>
#include <hip/hip_bf16.h>

// Sizes (fixed by the reference)
#define BATCH 8192
#define DIM   128
#define NPAT  64
#define VOCAB 32000
#define CHUNKS (BATCH / 16)   // 512 16-row A chunks

// GEMM geometry (R14, proven 244.6 us): 1000 blocks x 128 thr (2 waves).
// Wave owns 128 cols (8 tiles, b[8][4] = 128 VGPR), sweeps 64 chunks.
// Stores via 8-KB/wave XOR-swizzled LDS pad: each store instruction covers
// 2 rows x 512-B contiguous runs (write-BW curve: 64B=2.95, 256B=4.4,
// 512B=5.0, 1024B=4.9 TB/s -> 512B is the knee; 5 TB/s = store ceiling).
#define NPANEL  125
#define NSPLITS 8
#define CPB     (CHUNKS / NSPLITS)    // 64 chunks per wave

// prep kernel block split
#define PA_BLOCKS 2048                // phaseA: 4 rows each
#define RW_BLOCKS (VOCAB / 64)        // 500 repack_w blocks

typedef __attribute__((ext_vector_type(8))) short short8;   // 8 bf16 = 4 VGPRs
typedef __attribute__((ext_vector_type(4))) float f32x4;    // MFMA accum

// ---------------------------------------------------------------------------
// PREP (fused): blocks [0,2048) = phaseA writing Af DIRECTLY (fragment-major,
// no intermediate gated buffer); blocks [2048,2548) = repack_w (runs
// concurrently, hiding its ~5 us under phaseA).
// phaseA per block: 4 waves x 1 row. After the gate, rows staged as bf16 in
// padded LDS [4][136] (row stride 272 B -> writer lanes wid_r spread 4 banks
// apart, conflict-free); wave 0 emits the chunk-slice of Af in ONE 16-B/lane
// instruction: lane l = (ks=l>>4, kq=(l>>2)&3, wid_r=l&3) writes
// Af[((ch*4+ks)*64 + kq*16 + r16base+wid_r)*8 ..+8] = gs[wid_r][ks*32+kq*8..].
// ---------------------------------------------------------------------------
__global__ __launch_bounds__(256) void prep_kernel(
    const float* __restrict__ x,            // [B, D]
    const float* __restrict__ attn_w,       // [D, P]
    const float* __restrict__ attn_b,       // [P]
    const float* __restrict__ pattern_dict, // [P, D]
    const float* __restrict__ self_w,       // [D, D]
    const float* __restrict__ self_b,       // [D]
    const float* __restrict__ out_w,        // [D, V]
    __hip_bfloat16* __restrict__ Af,        // fragment-major A out
    __hip_bfloat16* __restrict__ Bf)        // fragment-major W out
{
    if (blockIdx.x < PA_BLOCKS) {
        // ---------------- phaseA + direct Af emit ----------------
        __shared__ float xs[4][DIM];
        __shared__ float wls[4][NPAT];
        __shared__ float recs[4][DIM];
        __shared__ __hip_bfloat16 gs[4][136];   // padded: 272-B row stride

        const int lane = threadIdx.x & 63;
        const int wid  = threadIdx.x >> 6;
        const int bidx = blockIdx.x;
        const int row  = bidx * 4 + wid;

        xs[wid][lane]      = x[row * DIM + lane];
        xs[wid][lane + 64] = x[row * DIM + 64 + lane];
        __syncthreads();

        float acc = attn_b[lane];
#pragma unroll 8
        for (int d = 0; d < DIM; ++d)
            acc += xs[wid][d] * attn_w[d * NPAT + lane];

        float m = acc;
#pragma unroll
        for (int o = 32; o; o >>= 1) m = fmaxf(m, __shfl_xor(m, o));
        float e = expf(acc - m);
        float s = e;
#pragma unroll
        for (int o = 32; o; o >>= 1) s += __shfl_xor(s, o);
        float w = e / s;
        wls[wid][lane] = w;
        __syncthreads();

        float r0 = 0.f, r1 = 0.f;
#pragma unroll 8
        for (int p = 0; p < NPAT; ++p) {
            float wp = wls[wid][p];
            r0 += wp * pattern_dict[p * DIM + lane];
            r1 += wp * pattern_dict[p * DIM + 64 + lane];
        }
        recs[wid][lane]      = r0;
        recs[wid][lane + 64] = r1;
        __syncthreads();

        float s0 = self_b[lane], s1 = self_b[lane + 64];
#pragma unroll 8
        for (int k = 0; k < DIM; ++k) {
            float rk = recs[wid][k];
            s0 += rk * self_w[k * DIM + lane];
            s1 += rk * self_w[k * DIM + 64 + lane];
        }

        float p0 = s0 - r0, p1 = s1 - r1;
        float ss = p0 * p0 + p1 * p1;
#pragma unroll
        for (int o = 32; o; o >>= 1) ss += __shfl_xor(ss, o);
        float mag = sqrtf(ss);
        float g = 1.f / (1.f + expf(-mag));

        gs[wid][lane]      = __float2bfloat16(r0 * g);
        gs[wid][lane + 64] = __float2bfloat16(r1 * g);
        __syncthreads();

        // wave 0 emits the 4 rows' Af fragments (64 x 16 B, one instruction)
        if (wid == 0) {
            const int ch      = bidx >> 2;
            const int r16base = (bidx & 3) * 4;
            const int ks    = lane >> 4;
            const int kq    = (lane >> 2) & 3;
            const int wid_r = lane & 3;
            uint4 v = *reinterpret_cast<const uint4*>(&gs[wid_r][ks * 32 + kq * 8]);
            *reinterpret_cast<uint4*>(
                Af + ((size_t)((ch * 4 + ks) * 64 + kq * 16 + r16base + wid_r)) * 8) = v;
        }
    } else {
        // ---------------- repack_w (proven R5-R15) ----------------
        __shared__ __hip_bfloat16 tile[64][136];

        const int t  = threadIdx.x;
        const int n0 = (blockIdx.x - PA_BLOCKS) * 64;
        const int c  = t & 63;
        const int k0 = t >> 6;

        for (int kk = 0; kk < DIM; kk += 4) {
            int k = kk + k0;
            tile[c][k] = __float2bfloat16(out_w[(size_t)k * VOCAB + n0 + c]);
        }
        __syncthreads();

        const int lane = t & 63;
        const int tl   = t >> 6;
        const int r16  = lane & 15;
        const int kq   = lane >> 4;
        const int gt   = (n0 >> 4) + tl;
#pragma unroll
        for (int ks = 0; ks < 4; ++ks) {
            uint4 v = *reinterpret_cast<const uint4*>(&tile[tl * 16 + r16][ks * 32 + kq * 8]);
            *reinterpret_cast<uint4*>(Bf + ((size_t)(gt * 4 + ks) * 64 + lane) * 8) = v;
        }
    }
}

// ---------------------------------------------------------------------------
// GEMM (R14, byte-identical; proven 244.6 us): barrier-free, 128-col waves,
// 512-B-per-row store runs via XOR-swizzled per-wave LDS pad. B-frags in
// registers; A in register ping-pong from L2-resident Af; bias = one
// f32x4/lane added at store.
// ---------------------------------------------------------------------------
__global__ __launch_bounds__(128, 2) void gemm_kernel(
    const __hip_bfloat16* __restrict__ Af,  // fragment-major A
    const __hip_bfloat16* __restrict__ Bf,  // fragment-major W
    const float* __restrict__ bias,         // [V]
    float* __restrict__ out)                // [B, V]
{
    __shared__ char epi[2][8192];           // per-wave pad: 16 rows x 512 B

    const int lane  = threadIdx.x & 63;
    const int w     = threadIdx.x >> 6;     // 0..1
    const int r16   = lane & 15;
    const int kq    = lane >> 4;            // 0..3
    const int rr    = lane >> 5;            // store row parity
    const int l31   = lane & 31;            // store col slot
    const int panel = blockIdx.x % NPANEL;
    const int split = blockIdx.x / NPANEL;  // 0..7
    const int col0  = panel * 256 + w * 128;
    const int t0    = panel * 16 + w * 8;   // first of 8 n-tiles
    const int ch0   = split * CPB;

    // B fragments for this wave's 8 tiles: registers for the whole kernel.
    short8 b[8][4];
#pragma unroll
    for (int t = 0; t < 8; ++t)
#pragma unroll
        for (int ks = 0; ks < 4; ++ks)
            b[t][ks] = *reinterpret_cast<const short8*>(
                Bf + ((size_t)((t0 + t) * 4 + ks) * 64 + lane) * 8);

    // bias: each lane's store column is fixed -> one f32x4 for the kernel.
    const f32x4 bb = *reinterpret_cast<const f32x4*>(bias + col0 + l31 * 4);

    char* pad = &epi[w][0];

    auto aload = [&](int ch, short8* a) {
#pragma unroll
        for (int ks = 0; ks < 4; ++ks)
            a[ks] = *reinterpret_cast<const short8*>(
                Af + ((size_t)(ch * 4 + ks) * 64 + lane) * 8);
    };

    short8 a0[4], a1[4];
    aload(ch0, a0);                          // prologue: first chunk

#pragma unroll 2
    for (int c = 0; c < CPB; ++c) {
        short8* acur = (c & 1) ? a1 : a0;
        short8* anxt = (c & 1) ? a0 : a1;
        const int ch = ch0 + c;

        if (c + 1 < CPB) aload(ch + 1, anxt); // prefetch next chunk into regs

        f32x4 acc[8];
#pragma unroll
        for (int t = 0; t < 8; ++t) {
            f32x4 z = {};
#pragma unroll
            for (int ks = 0; ks < 4; ++ks)
                z = __builtin_amdgcn_mfma_f32_16x16x32_bf16(
                    b[t][ks], acur[ks], z, 0, 0, 0);
            acc[t] = z;
        }

        // ---- epi pad write: row r16, colbytes t*64 + kq*16, XOR-swizzled ----
#pragma unroll
        for (int t = 0; t < 8; ++t) {
            const int pb = r16 * 512 + ((t * 64 + kq * 16) ^ ((r16 & 7) << 4));
            *reinterpret_cast<f32x4*>(pad + pb) = acc[t];
        }

        // ---- stores: 8 instrs x (2 rows x 512-B contiguous runs) ----
        const size_t orow0 = (size_t)ch * 16 * VOCAB + col0;
#pragma unroll
        for (int s = 0; s < 8; ++s) {
            const int row = 2 * s + rr;
            const int pb  = row * 512 + ((l31 * 16) ^ ((row & 7) << 4));
            f32x4 v = *reinterpret_cast<const f32x4*>(pad + pb);
            v += bb;
            *reinterpret_cast<f32x4*>(out + orow0 + (size_t)row * VOCAB + l31 * 4) = v;
        }
    }
}

// ---------------------------------------------------------------------------
extern "C" void kernel_launch(void* const* d_in, const int* in_sizes, int n_in,
                              void* d_out, int out_size, void* d_ws, size_t ws_size,
                              hipStream_t stream) {
    const float* x            = (const float*)d_in[0];
    const float* pattern_dict = (const float*)d_in[1];
    const float* attn_w       = (const float*)d_in[2];
    const float* attn_b       = (const float*)d_in[3];
    const float* self_w       = (const float*)d_in[4];
    const float* self_b       = (const float*)d_in[5];
    const float* out_w        = (const float*)d_in[6];
    const float* out_b        = (const float*)d_in[7];
    float* out = (float*)d_out;

    // ws: Af 2 MB | Bf 8.2 MB   (gated buffer eliminated)
    __hip_bfloat16* Af = (__hip_bfloat16*)d_ws;
    __hip_bfloat16* Bf = (__hip_bfloat16*)((char*)d_ws + (size_t)BATCH * DIM * 2);

    prep_kernel<<<PA_BLOCKS + RW_BLOCKS, 256, 0, stream>>>(
        x, attn_w, attn_b, pattern_dict, self_w, self_b, out_w, Af, Bf);
    gemm_kernel<<<NPANEL * NSPLITS, 128, 0, stream>>>(Af, Bf, out_b, out);
}